// Round 4
// baseline (13.407 us; speedup 1.0000x reference)
//
#include <hip/hip_runtime.h>

// Retina multi-scale glimpse, fused single-pass, channel-fused:
//   x: (128, 3, 224, 224) f32, l: (128, 2) f32 in [-1,1]
//   out: (128, 9, 32, 32) f32
//   r0,c0 = int(224*(l+1)/2); patch = edge-padded(x)[r0:r0+128, c0:c0+128] (pad=64)
//   ch 0-2: maxpool4(patch), ch 3-5: maxpool2(patch[32:96,32:96]), ch 6-8: patch[48:80,48:80]
//
// One thread owns one 4x4 patch tile position for ALL 3 channels:
// crop-origin math and clamped offsets computed once, 12 float4 loads
// (interior path), 3x outputs. 2048 waves total (was 6144) — attacks the
// wave-dispatch overhead that R1->R2 showed is the dominant cost.

#define IMG 224

__global__ __launch_bounds__(256) void retina_fused(
    const float* __restrict__ x, const float* __restrict__ l,
    float* __restrict__ out)
{
    int b   = blockIdx.x >> 2;                        // 4 blocks per batch
    int wid = ((blockIdx.x & 3) << 8) | threadIdx.x;  // 0..1023 tile position
    int tx  = wid & 31;
    int ty  = wid >> 5;

    // Match JAX op order exactly: (224 * (l + 1.0)) / 2.0, truncate to int.
    float l0 = l[b * 2 + 0];
    float l1 = l[b * 2 + 1];
    int r0 = (int)(224.0f * (l0 + 1.0f) / 2.0f);
    int c0 = (int)(224.0f * (l1 + 1.0f) / 2.0f);
    r0 = min(max(r0, 0), 224);
    c0 = min(max(c0, 0), 224);

    // Clamped row offsets (edge padding = clamp), channel-independent.
    int rowoff[4];
    #pragma unroll
    for (int d = 0; d < 4; ++d) {
        int sr = r0 + 4 * ty + d - 64;
        rowoff[d] = min(max(sr, 0), IMG - 1) * IMG;
    }

    int cbase = c0 + 4 * tx - 64;                 // leftmost source column
    bool interior = (cbase >= 0 && cbase <= IMG - 4);
    int coloff[4];
    #pragma unroll
    for (int d = 0; d < 4; ++d)
        coloff[d] = min(max(cbase + d, 0), IMG - 1);

    // Output-region membership, channel-independent.
    bool in1 = (ty >= 8  && ty < 24 && tx >= 8  && tx < 24);
    bool in2 = (ty >= 12 && ty < 20 && tx >= 12 && tx < 20);

    const float* __restrict__ xb0 = x + (size_t)(b * 3) * (IMG * IMG);
    float* __restrict__ ob = out + (size_t)(b * 9) * 1024;

    #pragma unroll
    for (int c = 0; c < 3; ++c) {
        const float* __restrict__ xb = xb0 + (size_t)c * (IMG * IMG);
        float v[4][4];
        if (interior) {
            #pragma unroll
            for (int dy = 0; dy < 4; ++dy) {
                float4 r4 = *reinterpret_cast<const float4*>(xb + rowoff[dy] + cbase);
                v[dy][0] = r4.x; v[dy][1] = r4.y; v[dy][2] = r4.z; v[dy][3] = r4.w;
            }
        } else {
            #pragma unroll
            for (int dy = 0; dy < 4; ++dy)
                #pragma unroll
                for (int dx = 0; dx < 4; ++dx)
                    v[dy][dx] = xb[rowoff[dy] + coloff[dx]];
        }

        // scale 0: 4x4 max
        float m01 = fmaxf(fmaxf(v[0][0], v[0][1]), fmaxf(v[0][2], v[0][3]));
        float m11 = fmaxf(fmaxf(v[1][0], v[1][1]), fmaxf(v[1][2], v[1][3]));
        float m21 = fmaxf(fmaxf(v[2][0], v[2][1]), fmaxf(v[2][2], v[2][3]));
        float m31 = fmaxf(fmaxf(v[3][0], v[3][1]), fmaxf(v[3][2], v[3][3]));
        float m0  = fmaxf(fmaxf(m01, m11), fmaxf(m21, m31));
        ob[(c << 10) + (ty << 5) + tx] = m0;

        // scale 1: central 64x64 -> ty,tx in [8,24)
        if (in1) {
            float* __restrict__ o1 = ob + ((3 + c) << 10);
            int oy = 2 * (ty - 8);
            int ox = 2 * (tx - 8);
            #pragma unroll
            for (int sy = 0; sy < 2; ++sy)
                #pragma unroll
                for (int sx = 0; sx < 2; ++sx) {
                    float q = fmaxf(fmaxf(v[2*sy][2*sx],   v[2*sy][2*sx+1]),
                                    fmaxf(v[2*sy+1][2*sx], v[2*sy+1][2*sx+1]));
                    o1[((oy + sy) << 5) + (ox + sx)] = q;
                }
        }

        // scale 2: central 32x32 -> ty,tx in [12,20); float4 stores (ox % 4 == 0)
        if (in2) {
            float* __restrict__ o2 = ob + ((6 + c) << 10);
            int oy = 4 * (ty - 12);
            int ox = 4 * (tx - 12);
            #pragma unroll
            for (int dy = 0; dy < 4; ++dy) {
                float4 s4 = make_float4(v[dy][0], v[dy][1], v[dy][2], v[dy][3]);
                *reinterpret_cast<float4*>(o2 + ((oy + dy) << 5) + ox) = s4;
            }
        }
    }
}

extern "C" void kernel_launch(void* const* d_in, const int* in_sizes, int n_in,
                              void* d_out, int out_size, void* d_ws, size_t ws_size,
                              hipStream_t stream) {
    const float* x = (const float*)d_in[0];
    const float* l = (const float*)d_in[1];
    float* out = (float*)d_out;

    const int total_threads = 128 * 32 * 32;   // 131,072 (one per b,ty,tx)
    int blocks = total_threads / 256;          // 512, exact
    retina_fused<<<blocks, 256, 0, stream>>>(x, l, out);
}

// Round 5
// 12.474 us; speedup vs baseline: 1.0748x; 1.0748x over previous
//
#include <hip/hip_runtime.h>

// Retina multi-scale glimpse, fused single-pass:
//   x: (128, 3, 224, 224) f32, l: (128, 2) f32 in [-1,1]
//   out: (128, 9, 32, 32) f32
//   r0,c0 = int(224*(l+1)/2); patch = edge-padded(x)[r0:r0+128, c0:c0+128] (pad=64)
//   ch 0-2: maxpool4(patch), ch 3-5: maxpool2(patch[32:96,32:96]), ch 6-8: patch[48:80,48:80]
//
// R5: R2/R3's per-(b,c,tile) decomposition (best measured: 6144 waves,
// 24 waves/CU) with 512-thread blocks -> 768 dispatches instead of 1536,
// occupancy unchanged. Tests whether block-dispatch rate contributes to the
// ~12.5 us floor.

#define IMG 224

__global__ __launch_bounds__(512) void retina_fused(
    const float* __restrict__ x, const float* __restrict__ l,
    float* __restrict__ out)
{
    // 2 blocks per (b,c); b,c block-uniform -> scalar l loads / crop math.
    int bc  = blockIdx.x >> 1;
    int b   = bc / 3;
    int c   = bc % 3;
    int wid = ((blockIdx.x & 1) << 9) | threadIdx.x;   // 0..1023 tile position
    int tx  = wid & 31;
    int ty  = wid >> 5;

    // Match JAX op order exactly: (224 * (l + 1.0)) / 2.0, truncate to int.
    float l0 = l[b * 2 + 0];
    float l1 = l[b * 2 + 1];
    int r0 = (int)(224.0f * (l0 + 1.0f) / 2.0f);
    int c0 = (int)(224.0f * (l1 + 1.0f) / 2.0f);
    r0 = min(max(r0, 0), 224);
    c0 = min(max(c0, 0), 224);

    const float* __restrict__ xb = x + (size_t)(b * 3 + c) * (IMG * IMG);

    // Clamped row offsets (edge padding = clamp), shared by the whole tile.
    int rowoff[4];
    #pragma unroll
    for (int d = 0; d < 4; ++d) {
        int sr = r0 + 4 * ty + d - 64;
        rowoff[d] = min(max(sr, 0), IMG - 1) * IMG;
    }

    float v[4][4];
    int cbase = c0 + 4 * tx - 64;                 // leftmost source column
    if (cbase >= 0 && cbase <= IMG - 4) {
        // Interior columns: one dwordx4 per row (dword-aligned is sufficient).
        #pragma unroll
        for (int dy = 0; dy < 4; ++dy) {
            float4 r4 = *reinterpret_cast<const float4*>(xb + rowoff[dy] + cbase);
            v[dy][0] = r4.x; v[dy][1] = r4.y; v[dy][2] = r4.z; v[dy][3] = r4.w;
        }
    } else {
        // Border tile: per-column clamp, scalar loads.
        int coloff[4];
        #pragma unroll
        for (int d = 0; d < 4; ++d)
            coloff[d] = min(max(cbase + d, 0), IMG - 1);
        #pragma unroll
        for (int dy = 0; dy < 4; ++dy)
            #pragma unroll
            for (int dx = 0; dx < 4; ++dx)
                v[dy][dx] = xb[rowoff[dy] + coloff[dx]];
    }

    // scale 0: 4x4 max
    float m01 = fmaxf(fmaxf(v[0][0], v[0][1]), fmaxf(v[0][2], v[0][3]));
    float m11 = fmaxf(fmaxf(v[1][0], v[1][1]), fmaxf(v[1][2], v[1][3]));
    float m21 = fmaxf(fmaxf(v[2][0], v[2][1]), fmaxf(v[2][2], v[2][3]));
    float m31 = fmaxf(fmaxf(v[3][0], v[3][1]), fmaxf(v[3][2], v[3][3]));
    float m0  = fmaxf(fmaxf(m01, m11), fmaxf(m21, m31));

    float* __restrict__ ob = out + (size_t)(b * 9) * 1024;
    ob[(c << 10) + (ty << 5) + tx] = m0;

    // scale 1: central 64x64 -> ty,tx in [8,24)
    if (ty >= 8 && ty < 24 && tx >= 8 && tx < 24) {
        float* __restrict__ o1 = ob + ((3 + c) << 10);
        int oy = 2 * (ty - 8);
        int ox = 2 * (tx - 8);
        #pragma unroll
        for (int sy = 0; sy < 2; ++sy)
            #pragma unroll
            for (int sx = 0; sx < 2; ++sx) {
                float q = fmaxf(fmaxf(v[2*sy][2*sx],   v[2*sy][2*sx+1]),
                                fmaxf(v[2*sy+1][2*sx], v[2*sy+1][2*sx+1]));
                o1[((oy + sy) << 5) + (ox + sx)] = q;
            }
    }

    // scale 2: central 32x32 -> ty,tx in [12,20); float4 stores (ox % 4 == 0)
    if (ty >= 12 && ty < 20 && tx >= 12 && tx < 20) {
        float* __restrict__ o2 = ob + ((6 + c) << 10);
        int oy = 4 * (ty - 12);
        int ox = 4 * (tx - 12);
        #pragma unroll
        for (int dy = 0; dy < 4; ++dy) {
            float4 s4 = make_float4(v[dy][0], v[dy][1], v[dy][2], v[dy][3]);
            *reinterpret_cast<float4*>(o2 + ((oy + dy) << 5) + ox) = s4;
        }
    }
}

extern "C" void kernel_launch(void* const* d_in, const int* in_sizes, int n_in,
                              void* d_out, int out_size, void* d_ws, size_t ws_size,
                              hipStream_t stream) {
    const float* x = (const float*)d_in[0];
    const float* l = (const float*)d_in[1];
    float* out = (float*)d_out;

    const int total_threads = 128 * 3 * 32 * 32;   // 393,216
    int blocks = total_threads / 512;              // 768, exact
    retina_fused<<<blocks, 512, 0, stream>>>(x, l, out);
}